// Round 1
// baseline (305.169 us; speedup 1.0000x reference)
//
#include <hip/hip_runtime.h>
#include <hip/hip_bf16.h>

// Householder reflection: out[b,:] = z[b,:] - 2*v[b,:]*(v.z)/(v.v)
// B=8192 rows, L=4096 fp32. Memory-bound: ideal 384 MiB HBM traffic.
// One block per row; stage v,z in LDS so the epilogue pass doesn't re-read HBM.

#define L_DIM 4096
#define BLOCK 256
#define VEC (L_DIM / 4)        // 1024 float4 per row
#define PER_THREAD (VEC / BLOCK) // 4 float4 per thread

__global__ __launch_bounds__(BLOCK) void householder_kernel(
    const float* __restrict__ v,
    const float* __restrict__ z,
    float* __restrict__ out)
{
    __shared__ float4 sv[VEC];
    __shared__ float4 sz[VEC];
    __shared__ float s_red[2][4];
    __shared__ float s_scale;

    const int row = blockIdx.x;
    const size_t base = (size_t)row * L_DIM;
    const float4* v4 = (const float4*)(v + base);
    const float4* z4 = (const float4*)(z + base);
    float4* o4 = (float4*)(out + base);

    float vz = 0.0f, vv = 0.0f;

    // Pass 1: load, stage to LDS, partial dot products.
    #pragma unroll
    for (int k = 0; k < PER_THREAD; ++k) {
        const int i = threadIdx.x + k * BLOCK;   // coalesced: consecutive lanes, consecutive float4
        float4 a = v4[i];
        float4 b = z4[i];
        sv[i] = a;
        sz[i] = b;
        vz = fmaf(a.x, b.x, vz); vz = fmaf(a.y, b.y, vz);
        vz = fmaf(a.z, b.z, vz); vz = fmaf(a.w, b.w, vz);
        vv = fmaf(a.x, a.x, vv); vv = fmaf(a.y, a.y, vv);
        vv = fmaf(a.z, a.z, vv); vv = fmaf(a.w, a.w, vv);
    }

    // Wave (64-lane) shuffle reduction.
    #pragma unroll
    for (int off = 32; off > 0; off >>= 1) {
        vz += __shfl_down(vz, off, 64);
        vv += __shfl_down(vv, off, 64);
    }

    const int wave = threadIdx.x >> 6;
    const int lane = threadIdx.x & 63;
    if (lane == 0) {
        s_red[0][wave] = vz;
        s_red[1][wave] = vv;
    }
    __syncthreads();

    if (threadIdx.x == 0) {
        float tvz = s_red[0][0] + s_red[0][1] + s_red[0][2] + s_red[0][3];
        float tvv = s_red[1][0] + s_red[1][1] + s_red[1][2] + s_red[1][3];
        s_scale = -2.0f * tvz / tvv;
    }
    __syncthreads();

    const float s = s_scale;

    // Pass 2: out = z + s*v, reading the staged LDS copies (no HBM re-read).
    #pragma unroll
    for (int k = 0; k < PER_THREAD; ++k) {
        const int i = threadIdx.x + k * BLOCK;
        float4 a = sv[i];
        float4 b = sz[i];
        float4 r;
        r.x = fmaf(s, a.x, b.x);
        r.y = fmaf(s, a.y, b.y);
        r.z = fmaf(s, a.z, b.z);
        r.w = fmaf(s, a.w, b.w);
        o4[i] = r;
    }
}

extern "C" void kernel_launch(void* const* d_in, const int* in_sizes, int n_in,
                              void* d_out, int out_size, void* d_ws, size_t ws_size,
                              hipStream_t stream) {
    const float* v = (const float*)d_in[0];
    const float* z = (const float*)d_in[1];
    float* out = (float*)d_out;
    const int B = in_sizes[0] / L_DIM;   // 8192
    householder_kernel<<<B, BLOCK, 0, stream>>>(v, z, out);
}